// Round 16
// baseline (385.239 us; speedup 1.0000x reference)
//
#include <hip/hip_runtime.h>

#define TB 128  // 2 waves; L1: wave0=fwd, wave1=bwd. L2/L3: wave0 carries both dirs.

typedef float v2f __attribute__((ext_vector_type(2)));
typedef _Float16 f16;
typedef _Float16 h2v __attribute__((ext_vector_type(2)));

__device__ __forceinline__ float rcp_f(float x) { return __builtin_amdgcn_rcpf(x); }
__device__ __forceinline__ float exp2_f(float x) { return __builtin_amdgcn_exp2f(x); }
__device__ __forceinline__ float dpp_xor2(float x) {  // lane^2: quad_perm [2,3,0,1]
  return __int_as_float(__builtin_amdgcn_update_dpp(0, __float_as_int(x), 0x4E, 0xF, 0xF, true));
}
__device__ __forceinline__ float dpp_xor1(float x) {  // lane^1: quad_perm [1,0,3,2]
  return __int_as_float(__builtin_amdgcn_update_dpp(0, __float_as_int(x), 0xB1, 0xF, 0xF, true));
}

#if __has_builtin(__builtin_amdgcn_fdot2)
__device__ __forceinline__ float fdot2(h2v a, h2v b, float c) {
  return __builtin_amdgcn_fdot2(a, b, c, false);
}
#else
__device__ __forceinline__ float fdot2(h2v a, h2v b, float c) {
  return fmaf((float)a.x, (float)b.x, fmaf((float)a.y, (float)b.y, c));
}
#endif

// Gate activations: weights pre-scaled by log2e; g-gate additionally folded so
// the cell state carries cs = -2*log2e*c and tanh(c) = 2*rcp(1+exp2(cs)) - 1
// needs no per-step scaling multiply (exact algebra; validated r14/r15).
#define AM_G (-5.7707801636f)
#define AB_G (2.8853900818f)

// Lane map (within direction's wl): lane = 4*j + tau. Quad j owns cell j; tau =
// gate (0:i 1:f 2:g 3:o). Full x-dot + full h-dot per lane; gate combine = 3
// quad-DPP ops. One LDS h round-trip per step (f16 state: 1 ds_write_b16 +
// 1-2 ds_read_b128), ds_read HOISTED right after the write (same-wave in-order
// DS forwards the RAW); xw-dot + prefetch + store issue under the pending wait.
template<int D, int H, int T, int INS, int OUTS, int DEPTH, bool HIN,
         bool POOL, bool TOUT, typename OutT, typename InT>
__device__ __forceinline__ void scan(const void* wv, const h2v* hrh,
                                     float bb, float am, float ab,
                                     const InT* in, OutT* out,
                                     int dir, int wl, f16* h16) {
  constexpr int NF4 = HIN ? (D / 8) : (D / 4);
  constexpr int NHW = H / 2;  // h2v words of h state
  const int tau = wl & 3;
  const int j = (wl >> 2) & (H - 1);
  const bool st = (tau == 1) && ((wl >> 2) < H);
  if (wl < H) h16[wl] = (f16)0.f;
  __builtin_amdgcn_wave_barrier();

  h2v hreg[NHW];
  auto ldh = [&]() {
    if constexpr (H == 16) {
      *(float4*)&hreg[0] = *(const float4*)(h16);
      *(float4*)&hreg[4] = *(const float4*)(h16 + 8);
    } else if constexpr (H == 8) {
      *(float4*)&hreg[0] = *(const float4*)(h16);
    } else {
      *(float2*)&hreg[0] = *(const float2*)(h16);
    }
  };
  ldh();
  __builtin_amdgcn_wave_barrier();

  int t = dir ? (T - 1) : 0;
  const int dt = dir ? -1 : 1;

  float4 bufs[DEPTH][NF4];
  auto ldin = [&](float4* dst, int tt) {  // clamp-free: callers stay in range
    const float4* p = (const float4*)((const char*)in + (size_t)tt * INS * sizeof(InT));
#pragma unroll
    for (int i = 0; i < NF4; ++i) dst[i] = p[i];
  };
  auto xwdot = [&](const float4* b) -> float {
    if constexpr (HIN) {
      const h2v* hp = (const h2v*)b;
      const h2v* wh = (const h2v*)wv;
      float a0 = bb, a1 = 0.f, a2 = 0.f, a3 = 0.f;
#pragma unroll
      for (int i = 0; i < D / 2; i += 4) {
        a0 = fdot2(wh[i + 0], hp[i + 0], a0);
        a1 = fdot2(wh[i + 1], hp[i + 1], a1);
        a2 = fdot2(wh[i + 2], hp[i + 2], a2);
        a3 = fdot2(wh[i + 3], hp[i + 3], a3);
      }
      return (a0 + a1) + (a2 + a3);
    } else {
      const float* c = (const float*)b;
      const float* wr = (const float*)wv;
      v2f q0 = {bb, 0.f}, q1 = {0.f, 0.f};
#pragma unroll
      for (int i = 0; i < D; i += 4) {
        q0 = __builtin_elementwise_fma(*(const v2f*)(wr + i), *(const v2f*)(c + i), q0);
        q1 = __builtin_elementwise_fma(*(const v2f*)(wr + i + 2), *(const v2f*)(c + i + 2), q1);
      }
      v2f qs = q0 + q1;
      return qs.x + qs.y;
    }
  };

#pragma unroll
  for (int k = 0; k < DEPTH; ++k) ldin(bufs[k], t + k * dt);
  float xw = xwdot(bufs[0]);
  float cs = 0.f, pm = 0.f;

  auto body = [&](int k, bool reload) {
    // h-dot from carried f16 registers (read was issued last iteration)
    float a0 = xw, a1 = 0.f;
#pragma unroll
    for (int i = 0; i < NHW; i += 2) {
      a0 = fdot2(hrh[i], hreg[i], a0);
      if (i + 1 < NHW) a1 = fdot2(hrh[i + 1], hreg[i + 1], a1);
    }
    float acc = a0 + a1;
    float sg = rcp_f(1.f + exp2_f(-acc));
    float a = fmaf(am, sg, ab);
    // quad combine: b = partner(^2): i<->g, f<->o ; q = (i*g') delivered ^1
    float b = dpp_xor2(a);
    float p = a * b;
    float q = dpp_xor1(p);
    float fv = (tau == 1) ? a : b;   // valid on tau1/tau3 (incl. all st lanes)
    float ov = (tau == 1) ? b : a;
    cs = fmaf(fv, cs, q);                          // cs = -2log2e * c
    float th = fmaf(2.f, rcp_f(1.f + exp2_f(cs)), -1.f);  // tanh(c)
    float hv = ov * th;
    if (st) h16[j] = (f16)hv;                      // ds_write_b16, 2-way free
    __builtin_amdgcn_wave_barrier();
    // hoisted read of the just-written h; wait overlaps with work below
    ldh();
    xw = xwdot(bufs[(k + 1) % DEPTH]);
    if (reload) ldin(bufs[k], t + DEPTH * dt);
    if (st) {
      if constexpr (TOUT) {
        out[(dir * H + j) * T + t] = (OutT)hv;
      } else if constexpr (POOL) {
        if (k & 1) out[(t >> 1) * OUTS + dir * H + j] = (OutT)fmaxf(pm, hv);
        else pm = hv;
      } else {
        out[t * OUTS + dir * H + j] = (OutT)hv;
      }
    }
    __builtin_amdgcn_wave_barrier();
    t += dt;
  };

  for (int so = 0; so < T / DEPTH - 1; ++so) {
#pragma unroll
    for (int k = 0; k < DEPTH; ++k) body(k, true);
  }
#pragma unroll
  for (int k = 0; k < DEPTH; ++k) body(k, false);  // epilogue: no reload
}

// f32 weight rows [2][4H][.] -> per-lane f16x2 input weights + f16x2 recurrent
// weights, pre-scaled by log2e (g-gate: cell-fold scaling).
template<int D, int H>
__device__ __forceinline__ void load_wbh(const float* __restrict__ wih,
                                         const float* __restrict__ whh,
                                         const float* __restrict__ bias,
                                         int dir, int wl,
                                         h2v* wh, h2v* hrh, float& bb,
                                         float& am, float& ab) {
  constexpr float L2E = 1.4426950408889634f;
  const int tau = wl & 3;
  const int j = (wl >> 2) & (H - 1);
  const bool isg = (tau == 2);
  const float k = isg ? 2.f * L2E : L2E;
  am = isg ? AM_G : 1.f;
  ab = isg ? AB_G : 0.f;
  const int row = dir * 4 * H + tau * H + j;
  const float* p = wih + row * D;
#pragma unroll
  for (int i = 0; i < D / 2; ++i)
    wh[i] = (h2v){(f16)(p[2 * i] * k), (f16)(p[2 * i + 1] * k)};
  const float* q = whh + row * H;
#pragma unroll
  for (int i = 0; i < H / 2; ++i)
    hrh[i] = (h2v){(f16)(q[2 * i] * k), (f16)(q[2 * i + 1] * k)};
  bb = bias[row] * k;
}

__global__ __launch_bounds__(TB) void lstm_all(
    const float* __restrict__ x,
    const float* __restrict__ conv_w, const float* __restrict__ conv_b,
    const float* __restrict__ bn_g, const float* __restrict__ bn_b,
    const float* __restrict__ bn_m, const float* __restrict__ bn_v,
    const float* __restrict__ w1a_ih, const float* __restrict__ w1a_hh, const float* __restrict__ b1a,
    const float* __restrict__ w1b_ih, const float* __restrict__ w1b_hh, const float* __restrict__ b1b,
    const float* __restrict__ w2a_ih, const float* __restrict__ w2a_hh, const float* __restrict__ b2a,
    const float* __restrict__ w2b_ih, const float* __restrict__ w2b_hh, const float* __restrict__ b2b,
    const float* __restrict__ w3_ih, const float* __restrict__ w3_hh, const float* __restrict__ b3,
    float* __restrict__ out, f16* __restrict__ ws, int row0) {
  const int row = row0 + blockIdx.x;
  const int tid = threadIdx.x;
  const int wave = tid >> 6;
  const int lane = tid & 63;

  // R1 (20 KB): phase1 xs16 f16[512][16] (16K); then LBh f16[256][32] (16K)
  // at +0 and LB2h f16[128][16] (4K) at +16384.
  __shared__ __align__(16) char R1[20480];
  __shared__ __align__(16) f16 A2h[256 * 16];  // 8 KB (L2a out / L2b in)
  __shared__ __align__(16) float w2c[64][11];
  __shared__ float b2c[64];
  __shared__ __align__(16) f16 hb16[2][16];  // h state (f16), 16 per direction

  f16 (*xs16)[16] = (f16(*)[16])R1;
  f16* LBh = (f16*)R1;
  f16* LB2h = (f16*)(R1 + 16384);
  f16* Ah = ws + (size_t)blockIdx.x * 16384;  // 32 KB per row (512*32 halves)

  // stage x[row] (11x512) transposed into LDS as f16; zero pad cols 11..15
  const float* xrow = x + (size_t)row * 5632;
  for (int i = tid; i < 5632; i += TB) {
    int c = i >> 9, t = i & 511;
    xs16[t][c] = (f16)xrow[i];
  }
  for (int i = tid; i < 512 * 5; i += TB) {
    int t = i / 5, c = 11 + i % 5;
    xs16[t][c] = (f16)0.f;
  }
  if (tid < 64) {
    float inv = bn_g[tid] * rsqrtf(bn_v[tid] + 1e-5f);
    for (int c = 0; c < 11; ++c) w2c[tid][c] = conv_w[tid * 11 + c] * inv;
    b2c[tid] = fmaf(conv_b[tid] - bn_m[tid], inv, bn_b[tid]);
  }
  __syncthreads();

  // ---- L1a: conv+BN folded into 16-wide effective f16 weights; dir = wave
  {
    constexpr float L2E = 1.4426950408889634f;
    const int tau = lane & 3;
    const int j = lane >> 2;  // 0..15
    const int row_l = wave * 64 + tau * 16 + j;
    float weff[16];
#pragma unroll
    for (int c = 0; c < 16; ++c) weff[c] = 0.f;
    const float* wih = w1a_ih + row_l * 64;
    float beff = b1a[row_l];
    for (int d = 0; d < 64; ++d) {
      float wd = wih[d];
      beff = fmaf(wd, b2c[d], beff);
#pragma unroll
      for (int c = 0; c < 11; ++c) weff[c] = fmaf(wd, w2c[d][c], weff[c]);
    }
    const bool isg = (tau == 2);
    const float k = isg ? 2.f * L2E : L2E;
    beff *= k;
    h2v weffh[8];
#pragma unroll
    for (int i = 0; i < 8; ++i)
      weffh[i] = (h2v){(f16)(weff[2 * i] * k), (f16)(weff[2 * i + 1] * k)};
    float am = isg ? AM_G : 1.f, ab = isg ? AB_G : 0.f;
    h2v hrh[8];
    const float* q = w1a_hh + row_l * 16;
#pragma unroll
    for (int i = 0; i < 8; ++i)
      hrh[i] = (h2v){(f16)(q[2 * i] * k), (f16)(q[2 * i + 1] * k)};
    // de-phase: offset wave1 by ~half a step so per-step stalls don't align
    if (wave) __builtin_amdgcn_s_sleep(4);
    // xs16 (LDS f16, D=16 padded) -> Ah (global f16), depth-2
    scan<16, 16, 512, 16, 32, 2, true, false, false, f16, f16>(
        weffh, hrh, beff, am, ab, &xs16[0][0], Ah, wave, lane, hb16[wave]);
  }
  __syncthreads();

  // ---- L1b + pool: Ah (global f16, depth-4 prefetch) -> LBh (LDS f16)
  {
    h2v wh[16]; h2v hrh[8]; float bb, am, ab;
    load_wbh<32, 16>(w1b_ih, w1b_hh, b1b, wave, lane, wh, hrh, bb, am, ab);
    if (wave) __builtin_amdgcn_s_sleep(4);
    scan<32, 16, 512, 32, 32, 4, true, true, false, f16, f16>(
        wh, hrh, bb, am, ab, Ah, LBh, wave, lane, hb16[wave]);
  }
  __syncthreads();

  // ---- L2a: LBh -> A2h; merged single wave (dir = lane>>5); wave1 idles
  if (wave == 0) {
    const int dir = lane >> 5, wl = lane & 31;
    h2v wh[16]; h2v hrh[4]; float bb, am, ab;
    load_wbh<32, 8>(w2a_ih, w2a_hh, b2a, dir, wl, wh, hrh, bb, am, ab);
    scan<32, 8, 256, 32, 16, 2, true, false, false, f16, f16>(
        wh, hrh, bb, am, ab, LBh, A2h, dir, wl, hb16[dir]);
  }
  __syncthreads();

  // ---- L2b + pool: A2h -> LB2h; merged
  if (wave == 0) {
    const int dir = lane >> 5, wl = lane & 31;
    h2v wh[8]; h2v hrh[4]; float bb, am, ab;
    load_wbh<16, 8>(w2b_ih, w2b_hh, b2b, dir, wl, wh, hrh, bb, am, ab);
    scan<16, 8, 256, 16, 16, 2, true, true, false, f16, f16>(
        wh, hrh, bb, am, ab, A2h, LB2h, dir, wl, hb16[dir]);
  }
  __syncthreads();

  // ---- L3: LB2h -> out[row][ch][t] (f32, transposed store); merged
  if (wave == 0) {
    const int dir = lane >> 5, wl = lane & 31;
    h2v wh[8]; h2v hrh[2]; float bb, am, ab;
    load_wbh<16, 4>(w3_ih, w3_hh, b3, dir, wl, wh, hrh, bb, am, ab);
    scan<16, 4, 128, 16, 8, 2, true, false, true, float, f16>(
        wh, hrh, bb, am, ab, LB2h, out + (size_t)row * 1024, dir, wl, hb16[dir]);
  }
}

extern "C" void kernel_launch(void* const* d_in, const int* in_sizes, int n_in,
                              void* d_out, int out_size, void* d_ws, size_t ws_size,
                              hipStream_t stream) {
  const float* x      = (const float*)d_in[0];
  const float* conv_w = (const float*)d_in[1];
  const float* conv_b = (const float*)d_in[2];
  const float* bn_g   = (const float*)d_in[3];
  const float* bn_b   = (const float*)d_in[4];
  const float* bn_m   = (const float*)d_in[5];
  const float* bn_v   = (const float*)d_in[6];
  const float* w1a_ih = (const float*)d_in[7];
  const float* w1a_hh = (const float*)d_in[8];
  const float* b1a    = (const float*)d_in[9];
  const float* w1b_ih = (const float*)d_in[10];
  const float* w1b_hh = (const float*)d_in[11];
  const float* b1b    = (const float*)d_in[12];
  const float* w2a_ih = (const float*)d_in[13];
  const float* w2a_hh = (const float*)d_in[14];
  const float* b2a    = (const float*)d_in[15];
  const float* w2b_ih = (const float*)d_in[16];
  const float* w2b_hh = (const float*)d_in[17];
  const float* b2b    = (const float*)d_in[18];
  const float* w3_ih  = (const float*)d_in[19];
  const float* w3_hh  = (const float*)d_in[20];
  const float* b3     = (const float*)d_in[21];

  const size_t per_row_bytes = 16384 * sizeof(f16);  // 32 KiB
  int rows_per = (int)(ws_size / per_row_bytes);
  if (rows_per < 1) rows_per = 1;
  if (rows_per > 1024) rows_per = 1024;

  for (int r0 = 0; r0 < 1024; r0 += rows_per) {
    int n = 1024 - r0;
    if (n > rows_per) n = rows_per;
    lstm_all<<<n, TB, 0, stream>>>(x, conv_w, conv_b, bn_g, bn_b, bn_m, bn_v,
                                   w1a_ih, w1a_hh, b1a, w1b_ih, w1b_hh, b1b,
                                   w2a_ih, w2a_hh, b2a, w2b_ih, w2b_hh, b2b,
                                   w3_ih, w3_hh, b3,
                                   (float*)d_out, (f16*)d_ws, r0);
  }
}

// Round 17
// 372.194 us; speedup vs baseline: 1.0350x; 1.0350x over previous
//
#include <hip/hip_runtime.h>

#define TB 128  // 2 waves; L1: wave0=fwd, wave1=bwd. L2/L3: wave0 carries both dirs.

typedef float v2f __attribute__((ext_vector_type(2)));
typedef _Float16 f16;
typedef _Float16 h2v __attribute__((ext_vector_type(2)));

__device__ __forceinline__ float rcp_f(float x) { return __builtin_amdgcn_rcpf(x); }
__device__ __forceinline__ float exp2_f(float x) { return __builtin_amdgcn_exp2f(x); }
__device__ __forceinline__ float dpp_xor2(float x) {  // lane^2: quad_perm [2,3,0,1]
  return __int_as_float(__builtin_amdgcn_update_dpp(0, __float_as_int(x), 0x4E, 0xF, 0xF, true));
}
__device__ __forceinline__ float dpp_xor1(float x) {  // lane^1: quad_perm [1,0,3,2]
  return __int_as_float(__builtin_amdgcn_update_dpp(0, __float_as_int(x), 0xB1, 0xF, 0xF, true));
}

#if __has_builtin(__builtin_amdgcn_fdot2)
__device__ __forceinline__ float fdot2(h2v a, h2v b, float c) {
  return __builtin_amdgcn_fdot2(a, b, c, false);
}
#else
__device__ __forceinline__ float fdot2(h2v a, h2v b, float c) {
  return fmaf((float)a.x, (float)b.x, fmaf((float)a.y, (float)b.y, c));
}
#endif

// Gate activations: weights pre-scaled by log2e; g-gate additionally folded so
// the cell state carries cs = -2*log2e*c and tanh(c) = 2*rcp(1+exp2(cs)) - 1
// needs no per-step scaling multiply (exact algebra; validated r14/r15).
#define AM_G (-5.7707801636f)
#define AB_G (2.8853900818f)

// Lane map (within direction's wl): lane = 4*j + tau. Quad j owns cell j; tau =
// gate (0:i 1:f 2:g 3:o). Full x-dot + full h-dot per lane; gate combine = 3
// quad-DPP ops. One LDS h round-trip per step, with the ds_read HOISTED to
// directly after the ds_write (same-wave in-order DS forwards the RAW); the
// xw-dot + prefetch + store issue under the pending lgkmcnt.
template<int D, int H, int T, int INS, int OUTS, int DEPTH, bool HIN,
         bool POOL, bool TOUT, typename OutT, typename InT>
__device__ __forceinline__ void scan(const void* wv, const float* hr,
                                     float bb, float am, float ab,
                                     const InT* in, OutT* out,
                                     int dir, int wl, float* h_base) {
  constexpr int NF4 = HIN ? (D / 8) : (D / 4);
  constexpr int NH4 = H / 4;
  const int tau = wl & 3;
  const int j = (wl >> 2) & (H - 1);
  const bool st = (tau == 1) && ((wl >> 2) < H);
  if (wl < H) h_base[wl] = 0.f;
  __builtin_amdgcn_wave_barrier();
  float4 hreg[NH4];
#pragma unroll
  for (int i = 0; i < NH4; ++i) hreg[i] = *(const float4*)(h_base + 4 * i);
  __builtin_amdgcn_wave_barrier();

  int t = dir ? (T - 1) : 0;
  const int dt = dir ? -1 : 1;

  float4 bufs[DEPTH][NF4];
  auto ldin = [&](float4* dst, int tt) {
    tt = tt < 0 ? 0 : (tt > T - 1 ? T - 1 : tt);
    const float4* p = (const float4*)((const char*)in + (size_t)tt * INS * sizeof(InT));
#pragma unroll
    for (int i = 0; i < NF4; ++i) dst[i] = p[i];
  };
  auto xwdot = [&](const float4* b) -> float {
    if constexpr (HIN) {
      const h2v* hp = (const h2v*)b;
      const h2v* wh = (const h2v*)wv;
      float a0 = bb, a1 = 0.f, a2 = 0.f, a3 = 0.f;
#pragma unroll
      for (int i = 0; i < D / 2; i += 4) {
        a0 = fdot2(wh[i + 0], hp[i + 0], a0);
        a1 = fdot2(wh[i + 1], hp[i + 1], a1);
        a2 = fdot2(wh[i + 2], hp[i + 2], a2);
        a3 = fdot2(wh[i + 3], hp[i + 3], a3);
      }
      return (a0 + a1) + (a2 + a3);
    } else {
      const float* c = (const float*)b;
      const float* wr = (const float*)wv;
      v2f q0 = {bb, 0.f}, q1 = {0.f, 0.f};
#pragma unroll
      for (int i = 0; i < D; i += 4) {
        q0 = __builtin_elementwise_fma(*(const v2f*)(wr + i), *(const v2f*)(c + i), q0);
        q1 = __builtin_elementwise_fma(*(const v2f*)(wr + i + 2), *(const v2f*)(c + i + 2), q1);
      }
      v2f qs = q0 + q1;
      return qs.x + qs.y;
    }
  };

#pragma unroll
  for (int k = 0; k < DEPTH; ++k) ldin(bufs[k], t + k * dt);
  float xw = xwdot(bufs[0]);
  float cs = 0.f, pm = 0.f;

  for (int s = 0; s < T; s += DEPTH) {
#pragma unroll
    for (int k = 0; k < DEPTH; ++k) {
      // h-dot from carried registers (read was issued last iteration)
      v2f r0 = {xw, 0.f}, r1 = {0.f, 0.f};
#pragma unroll
      for (int i = 0; i < NH4; ++i) {
        r0 = __builtin_elementwise_fma(*(const v2f*)(hr + 4 * i), (v2f){hreg[i].x, hreg[i].y}, r0);
        r1 = __builtin_elementwise_fma(*(const v2f*)(hr + 4 * i + 2), (v2f){hreg[i].z, hreg[i].w}, r1);
      }
      v2f rs = r0 + r1;
      float acc = rs.x + rs.y;
      float sg = rcp_f(1.f + exp2_f(-acc));
      float a = fmaf(am, sg, ab);
      // quad combine: b = partner(^2): i<->g, f<->o ; q = (i*g') delivered ^1
      float b = dpp_xor2(a);
      float p = a * b;
      float q = dpp_xor1(p);
      float fv = (tau == 1) ? a : b;   // valid on tau1/tau3 (incl. all st lanes)
      float ov = (tau == 1) ? b : a;
      cs = fmaf(fv, cs, q);                          // cs = -2log2e * c
      float th = fmaf(2.f, rcp_f(1.f + exp2_f(cs)), -1.f);  // tanh(c)
      float hv = ov * th;
      if (st) h_base[j] = hv;                        // 16 distinct banks
      __builtin_amdgcn_wave_barrier();
      // hoisted read of the just-written h; wait overlaps with work below
#pragma unroll
      for (int i = 0; i < NH4; ++i) hreg[i] = *(const float4*)(h_base + 4 * i);
      xw = xwdot(bufs[(k + 1) % DEPTH]);
      ldin(bufs[k], t + DEPTH * dt);
      if (st) {
        if constexpr (TOUT) {
          out[(dir * H + j) * T + t] = (OutT)hv;
        } else if constexpr (POOL) {
          if (k & 1) out[(t >> 1) * OUTS + dir * H + j] = (OutT)fmaxf(pm, hv);
          else pm = hv;
        } else {
          out[t * OUTS + dir * H + j] = (OutT)hv;
        }
      }
      __builtin_amdgcn_wave_barrier();
      t += dt;
    }
  }
}

// f32 weight rows [2][4H][.] -> per-lane f16x2 input weights + f32 recurrent
// weights, pre-scaled by log2e (g-gate: cell-fold scaling).
template<int D, int H>
__device__ __forceinline__ void load_wbh(const float* __restrict__ wih,
                                         const float* __restrict__ whh,
                                         const float* __restrict__ bias,
                                         int dir, int wl,
                                         h2v* wh, float* hr, float& bb,
                                         float& am, float& ab) {
  constexpr float L2E = 1.4426950408889634f;
  const int tau = wl & 3;
  const int j = (wl >> 2) & (H - 1);
  const bool isg = (tau == 2);
  const float k = isg ? 2.f * L2E : L2E;
  am = isg ? AM_G : 1.f;
  ab = isg ? AB_G : 0.f;
  const int row = dir * 4 * H + tau * H + j;
  const float* p = wih + row * D;
#pragma unroll
  for (int i = 0; i < D / 2; ++i)
    wh[i] = (h2v){(f16)(p[2 * i] * k), (f16)(p[2 * i + 1] * k)};
  const float* q = whh + row * H;
#pragma unroll
  for (int i = 0; i < H; ++i) hr[i] = q[i] * k;
  bb = bias[row] * k;
}

__global__ __launch_bounds__(TB) void lstm_all(
    const float* __restrict__ x,
    const float* __restrict__ conv_w, const float* __restrict__ conv_b,
    const float* __restrict__ bn_g, const float* __restrict__ bn_b,
    const float* __restrict__ bn_m, const float* __restrict__ bn_v,
    const float* __restrict__ w1a_ih, const float* __restrict__ w1a_hh, const float* __restrict__ b1a,
    const float* __restrict__ w1b_ih, const float* __restrict__ w1b_hh, const float* __restrict__ b1b,
    const float* __restrict__ w2a_ih, const float* __restrict__ w2a_hh, const float* __restrict__ b2a,
    const float* __restrict__ w2b_ih, const float* __restrict__ w2b_hh, const float* __restrict__ b2b,
    const float* __restrict__ w3_ih, const float* __restrict__ w3_hh, const float* __restrict__ b3,
    float* __restrict__ out, f16* __restrict__ ws, int row0) {
  const int row = row0 + blockIdx.x;
  const int tid = threadIdx.x;
  const int wave = tid >> 6;
  const int lane = tid & 63;

  // R1 (24 KB): phase1 xs f32[512][12]; later LBh f16[256][32] (16K) at +0
  // and LB2h f16[128][16] (4K) at +16384.
  __shared__ __align__(16) char R1[24576];
  __shared__ __align__(16) f16 A2h[256 * 16];  // 8 KB (L2a out / L2b in)
  __shared__ __align__(16) float w2c[64][11];
  __shared__ float b2c[64];
  __shared__ __align__(16) float hb[32];  // h state, 16 per direction

  float (*xs)[12] = (float(*)[12])R1;
  f16* LBh = (f16*)R1;
  f16* LB2h = (f16*)(R1 + 16384);
  f16* Ah = ws + (size_t)blockIdx.x * 16384;  // 32 KB per row (512*32 halves)

  // stage x[row] (11x512) transposed into LDS; zero pad col
  const float* xrow = x + (size_t)row * 5632;
  for (int i = tid; i < 5632; i += TB) {
    int c = i >> 9, t = i & 511;
    xs[t][c] = xrow[i];
  }
  for (int i = tid; i < 512; i += TB) xs[i][11] = 0.f;
  if (tid < 64) {
    float inv = bn_g[tid] * rsqrtf(bn_v[tid] + 1e-5f);
    for (int c = 0; c < 11; ++c) w2c[tid][c] = conv_w[tid * 11 + c] * inv;
    b2c[tid] = fmaf(conv_b[tid] - bn_m[tid], inv, bn_b[tid]);
  }
  __syncthreads();

  // ---- L1a: conv+BN folded into 12-wide effective f32 weights; dir = wave
  {
    constexpr float L2E = 1.4426950408889634f;
    const int tau = lane & 3;
    const int j = lane >> 2;  // 0..15
    const int row_l = wave * 64 + tau * 16 + j;
    float weff[12], beff;
#pragma unroll
    for (int c = 0; c < 12; ++c) weff[c] = 0.f;
    const float* wih = w1a_ih + row_l * 64;
    beff = b1a[row_l];
    for (int d = 0; d < 64; ++d) {
      float wd = wih[d];
      beff = fmaf(wd, b2c[d], beff);
#pragma unroll
      for (int c = 0; c < 11; ++c) weff[c] = fmaf(wd, w2c[d][c], weff[c]);
    }
    const bool isg = (tau == 2);
    const float k = isg ? 2.f * L2E : L2E;
#pragma unroll
    for (int c = 0; c < 12; ++c) weff[c] *= k;
    beff *= k;
    float am = isg ? AM_G : 1.f, ab = isg ? AB_G : 0.f;
    float hrw[16];
    const float* q = w1a_hh + row_l * 16;
#pragma unroll
    for (int i = 0; i < 16; ++i) hrw[i] = q[i] * k;
    // de-phase: offset wave1 by ~half a step so the two waves' per-step
    // stalls (DS round-trip + transcendentals) stop aligning on the SIMD.
    if (wave) __builtin_amdgcn_s_sleep(4);
    // xs (LDS f32) -> Ah (global f16), depth-2
    scan<12, 16, 512, 12, 32, 2, false, false, false, f16, float>(
        weff, hrw, beff, am, ab, &xs[0][0], Ah, wave, lane, hb + wave * 16);
  }
  __syncthreads();

  // ---- L1b + pool: Ah (global f16, depth-4 prefetch) -> LBh (LDS f16)
  {
    h2v wh[16]; float hr[16], bb, am, ab;
    load_wbh<32, 16>(w1b_ih, w1b_hh, b1b, wave, lane, wh, hr, bb, am, ab);
    if (wave) __builtin_amdgcn_s_sleep(4);
    scan<32, 16, 512, 32, 32, 4, true, true, false, f16, f16>(
        wh, hr, bb, am, ab, Ah, LBh, wave, lane, hb + wave * 16);
  }
  __syncthreads();

  // ---- L2a: LBh -> A2h; merged single wave (dir = lane>>5); wave1 idles
  if (wave == 0) {
    const int dir = lane >> 5, wl = lane & 31;
    h2v wh[16]; float hr[8], bb, am, ab;
    load_wbh<32, 8>(w2a_ih, w2a_hh, b2a, dir, wl, wh, hr, bb, am, ab);
    scan<32, 8, 256, 32, 16, 2, true, false, false, f16, f16>(
        wh, hr, bb, am, ab, LBh, A2h, dir, wl, hb + dir * 16);
  }
  __syncthreads();

  // ---- L2b + pool: A2h -> LB2h; merged
  if (wave == 0) {
    const int dir = lane >> 5, wl = lane & 31;
    h2v wh[8]; float hr[8], bb, am, ab;
    load_wbh<16, 8>(w2b_ih, w2b_hh, b2b, dir, wl, wh, hr, bb, am, ab);
    scan<16, 8, 256, 16, 16, 2, true, true, false, f16, f16>(
        wh, hr, bb, am, ab, A2h, LB2h, dir, wl, hb + dir * 16);
  }
  __syncthreads();

  // ---- L3: LB2h -> out[row][ch][t] (f32, transposed store); merged
  if (wave == 0) {
    const int dir = lane >> 5, wl = lane & 31;
    h2v wh[8]; float hr[4], bb, am, ab;
    load_wbh<16, 4>(w3_ih, w3_hh, b3, dir, wl, wh, hr, bb, am, ab);
    scan<16, 4, 128, 16, 8, 2, true, false, true, float, f16>(
        wh, hr, bb, am, ab, LB2h, out + (size_t)row * 1024, dir, wl, hb + dir * 16);
  }
}

extern "C" void kernel_launch(void* const* d_in, const int* in_sizes, int n_in,
                              void* d_out, int out_size, void* d_ws, size_t ws_size,
                              hipStream_t stream) {
  const float* x      = (const float*)d_in[0];
  const float* conv_w = (const float*)d_in[1];
  const float* conv_b = (const float*)d_in[2];
  const float* bn_g   = (const float*)d_in[3];
  const float* bn_b   = (const float*)d_in[4];
  const float* bn_m   = (const float*)d_in[5];
  const float* bn_v   = (const float*)d_in[6];
  const float* w1a_ih = (const float*)d_in[7];
  const float* w1a_hh = (const float*)d_in[8];
  const float* b1a    = (const float*)d_in[9];
  const float* w1b_ih = (const float*)d_in[10];
  const float* w1b_hh = (const float*)d_in[11];
  const float* b1b    = (const float*)d_in[12];
  const float* w2a_ih = (const float*)d_in[13];
  const float* w2a_hh = (const float*)d_in[14];
  const float* b2a    = (const float*)d_in[15];
  const float* w2b_ih = (const float*)d_in[16];
  const float* w2b_hh = (const float*)d_in[17];
  const float* b2b    = (const float*)d_in[18];
  const float* w3_ih  = (const float*)d_in[19];
  const float* w3_hh  = (const float*)d_in[20];
  const float* b3     = (const float*)d_in[21];

  const size_t per_row_bytes = 16384 * sizeof(f16);  // 32 KiB
  int rows_per = (int)(ws_size / per_row_bytes);
  if (rows_per < 1) rows_per = 1;
  if (rows_per > 1024) rows_per = 1024;

  for (int r0 = 0; r0 < 1024; r0 += rows_per) {
    int n = 1024 - r0;
    if (n > rows_per) n = rows_per;
    lstm_all<<<n, TB, 0, stream>>>(x, conv_w, conv_b, bn_g, bn_b, bn_m, bn_v,
                                   w1a_ih, w1a_hh, b1a, w1b_ih, w1b_hh, b1b,
                                   w2a_ih, w2a_hh, b2a, w2b_ih, w2b_hh, b2b,
                                   w3_ih, w3_hh, b3,
                                   (float*)d_out, (f16*)d_ws, r0);
  }
}